// Round 5
// baseline (695.641 us; speedup 1.0000x reference)
//
#include <hip/hip_runtime.h>
#include <hip/hip_bf16.h>

#define N_NODES 50000
#define N_EDGES 800000
#define IN_DIM  256
#define OUT_DIM 128

#define NBINS      256        // bins of 196 rows: 256*196 = 50176 >= 50000
#define ROWS_PER_BIN 196
#define BIN_CAP    3600       // mean 3125 + 8.5 sigma (sigma ~ 55.8)
#define EDGES_PER_BLK 4096    // k_bin tile

typedef __bf16 bf16x8 __attribute__((ext_vector_type(8)));
typedef float  f32x4  __attribute__((ext_vector_type(4)));

// bin = floor(row/196) via magic: (row * 85599) >> 24, exact for row < 50176
__device__ __forceinline__ unsigned bin_of(unsigned r) { return (r * 85599u) >> 24; }

__device__ __forceinline__ float blo(unsigned u) { return __uint_as_float(u << 16); }
__device__ __forceinline__ float bhi(unsigned u) { return __uint_as_float(u & 0xffff0000u); }

// ---------------------------------------------------------------------------
// ws layout (bytes)
// ---------------------------------------------------------------------------
#define WT_OFF   0                      // 64 KB    : Wt bf16 [128][256]
#define SUP_OFF  65536                  // 12.8 MB  : support u32 [50000][64] planar-pair
#define BIN_OFF  12865536               // 7.37 MB  : binbuf int2[256*3600]
#define CUR_OFF  20238336               // 1 KB     : bin_cursor int[256]

// ---------------------------------------------------------------------------
// prep: Wt transpose+bf16; bin_cursor[b] = b*BIN_CAP
// ---------------------------------------------------------------------------
__global__ void k_prep(const float* __restrict__ W, __bf16* __restrict__ Wt,
                       int* __restrict__ bin_cursor) {
    int t = blockIdx.x * 256 + threadIdx.x;
    if (t < 32768) { int n = t >> 8, k = t & 255; Wt[t] = (__bf16)W[k * OUT_DIM + n]; }
    if (t < NBINS) bin_cursor[t] = t * BIN_CAP;
}

// ---------------------------------------------------------------------------
// support = x @ W  (bf16 MFMA, fp32 accum). Epilogue stores planar-pair:
// word j of row = bf16(ch j) | bf16(ch j+64)<<16.
// C/D map: row = quad*4+r, col = nt*16+m  (verified R1-R4).
// ---------------------------------------------------------------------------
__global__ __launch_bounds__(256) void k_gemm(const float* __restrict__ x,
                                              const __bf16* __restrict__ Wt,
                                              unsigned* __restrict__ sup32) {
    int wave = threadIdx.x >> 6;
    int lane = threadIdx.x & 63;
    int tile = blockIdx.x * 4 + wave;
    if (tile >= 3125) return;
    int r0   = tile * 16;
    int m    = lane & 15;
    int quad = lane >> 4;

    f32x4 acc[8];
#pragma unroll
    for (int i = 0; i < 8; ++i) acc[i] = (f32x4){0.f, 0.f, 0.f, 0.f};

    const float*  xp = x  + (long)(r0 + m) * IN_DIM + quad * 8;
    const __bf16* wp = Wt + m * IN_DIM + quad * 8;

#pragma unroll
    for (int ks = 0; ks < 8; ++ks) {
        float4 a0 = *(const float4*)(xp + ks * 32);
        float4 a1 = *(const float4*)(xp + ks * 32 + 4);
        bf16x8 a;
        a[0] = (__bf16)a0.x; a[1] = (__bf16)a0.y;
        a[2] = (__bf16)a0.z; a[3] = (__bf16)a0.w;
        a[4] = (__bf16)a1.x; a[5] = (__bf16)a1.y;
        a[6] = (__bf16)a1.z; a[7] = (__bf16)a1.w;
#pragma unroll
        for (int nt = 0; nt < 8; ++nt) {
            bf16x8 bfr = *(const bf16x8*)(wp + nt * 16 * IN_DIM + ks * 32);
            acc[nt] = __builtin_amdgcn_mfma_f32_16x16x32_bf16(a, bfr, acc[nt], 0, 0, 0);
        }
    }

    unsigned* op = sup32 + (long)r0 * 64;
#pragma unroll
    for (int nt = 0; nt < 4; ++nt) {
#pragma unroll
        for (int r = 0; r < 4; ++r) {
            __bf16 lo = (__bf16)acc[nt][r];        // ch j     = nt*16+m (<64)
            __bf16 hi = (__bf16)acc[nt + 4][r];    // ch j+64  = (nt+4)*16+m
            unsigned ul = *(unsigned short*)&lo;
            unsigned uh = *(unsigned short*)&hi;
            op[(quad * 4 + r) * 64 + nt * 16 + m] = ul | (uh << 16);
        }
    }
}

// ---------------------------------------------------------------------------
// k_bin: LDS-staged bin sort. Per block: count -> scan -> LDS scatter ->
// one global reservation per bin -> coalesced sequential copy-out.
// Record: {row<<16|col, val bits}.
// ---------------------------------------------------------------------------
__global__ __launch_bounds__(256) void k_bin(const int* __restrict__ rows,
                                             const int* __restrict__ cols,
                                             const float* __restrict__ vals,
                                             int* __restrict__ bin_cursor,
                                             int2* __restrict__ binbuf) {
    __shared__ int2 stage[EDGES_PER_BLK];          // 32 KB
    __shared__ int  cnt[NBINS], off[NBINS], base[NBINS], cur[NBINS], s[NBINS];
    int t = threadIdx.x;
    long e0 = (long)blockIdx.x * EDGES_PER_BLK;

    cnt[t] = 0;
    __syncthreads();

    // phase 1: histogram (LDS atomics)
#pragma unroll
    for (int k = 0; k < 16; ++k) {
        long e = e0 + k * 256 + t;
        if (e < N_EDGES) atomicAdd(&cnt[bin_of((unsigned)rows[e])], 1);
    }
    __syncthreads();

    // phase 2: exclusive scan cnt -> off, global reservation -> base
    int v = cnt[t];
    s[t] = v; __syncthreads();
#pragma unroll
    for (int o = 1; o < 256; o <<= 1) {
        int xvl = (t >= o) ? s[t - o] : 0;
        __syncthreads();
        s[t] += xvl;
        __syncthreads();
    }
    off[t] = s[t] - v;
    cur[t] = s[t] - v;
    base[t] = atomicAdd(&bin_cursor[t], v);        // one global atomic per bin
    __syncthreads();

    // phase 3: scatter records into LDS stage, sorted by bin
#pragma unroll
    for (int k = 0; k < 16; ++k) {
        long e = e0 + k * 256 + t;
        if (e < N_EDGES) {
            unsigned r = (unsigned)rows[e];
            unsigned c = (unsigned)cols[e];
            float    w = vals[e];
            int pos = atomicAdd(&cur[bin_of(r)], 1);
            stage[pos] = make_int2((int)((r << 16) | c), __float_as_int(w));
        }
    }
    __syncthreads();

    // phase 4: coalesced copy-out (consecutive i -> consecutive dst per bin run)
    int nblk = (int)((N_EDGES - e0) < EDGES_PER_BLK ? (N_EDGES - e0) : EDGES_PER_BLK);
    for (int i = t; i < nblk; i += 256) {
        int2 rec = stage[i];
        unsigned bn = bin_of(((unsigned)rec.x) >> 16);
        int dst = base[bn] + (i - off[bn]);
        if (dst < (int)(bn + 1) * BIN_CAP)         // overflow guard (never at 8.5 sigma)
            binbuf[dst] = rec;
    }
}

// ---------------------------------------------------------------------------
// k_acc: one block per bin (256 blocks ~ 256 CUs). LDS fp32 tile 196x128.
// Per edge: wave reads planar-pair support word (4 B/lane coalesced),
// ds_add_f32 into acc (bank-stride 1 -> 2 lanes/bank, conflict-free).
// Final: sequential out write with bias fused.
// ---------------------------------------------------------------------------
__global__ __launch_bounds__(1024) void k_acc(const int* __restrict__ bin_cursor,
                                              const int2* __restrict__ binbuf,
                                              const unsigned* __restrict__ sup32,
                                              const float* __restrict__ b,
                                              float* __restrict__ out) {
    __shared__ float acc[ROWS_PER_BIN * 128];      // 100,352 B
    int bin  = blockIdx.x;
    int t    = threadIdx.x;
    int wave = t >> 6;
    int lane = t & 63;
    int row0 = bin * ROWS_PER_BIN;

    for (int i = t; i < ROWS_PER_BIN * 128; i += 1024) acc[i] = 0.f;
    __syncthreads();

    int n = bin_cursor[bin] - bin * BIN_CAP;
    n = n < 0 ? 0 : (n > BIN_CAP ? BIN_CAP : n);
    const int2* seg = binbuf + (long)bin * BIN_CAP;

    int i = wave;
    for (; i + 16 < n; i += 32) {                  // 2-deep MLP
        int2 r1 = seg[i];
        int2 r2 = seg[i + 16];
        unsigned c1 = ((unsigned)r1.x) & 0xffffu;
        unsigned c2 = ((unsigned)r2.x) & 0xffffu;
        unsigned u1 = sup32[(long)c1 * 64 + lane];
        unsigned u2 = sup32[(long)c2 * 64 + lane];
        float v1 = __int_as_float(r1.y);
        float v2 = __int_as_float(r2.y);
        int rl1 = (int)(((unsigned)r1.x) >> 16) - row0;
        int rl2 = (int)(((unsigned)r2.x) >> 16) - row0;
        atomicAdd(&acc[rl1 * 128 + lane],      v1 * blo(u1));
        atomicAdd(&acc[rl1 * 128 + 64 + lane], v1 * bhi(u1));
        atomicAdd(&acc[rl2 * 128 + lane],      v2 * blo(u2));
        atomicAdd(&acc[rl2 * 128 + 64 + lane], v2 * bhi(u2));
    }
    for (; i < n; i += 16) {
        int2 r1 = seg[i];
        unsigned c1 = ((unsigned)r1.x) & 0xffffu;
        unsigned u1 = sup32[(long)c1 * 64 + lane];
        float v1 = __int_as_float(r1.y);
        int rl1 = (int)(((unsigned)r1.x) >> 16) - row0;
        atomicAdd(&acc[rl1 * 128 + lane],      v1 * blo(u1));
        atomicAdd(&acc[rl1 * 128 + 64 + lane], v1 * bhi(u1));
    }
    __syncthreads();

    for (int idx = t; idx < ROWS_PER_BIN * 128; idx += 1024) {
        int r = row0 + (idx >> 7);
        if (r < N_NODES)
            out[(long)r * 128 + (idx & 127)] = acc[idx] + b[idx & 127];
    }
}

// ---------------------------------------------------------------------------
extern "C" void kernel_launch(void* const* d_in, const int* in_sizes, int n_in,
                              void* d_out, int out_size, void* d_ws, size_t ws_size,
                              hipStream_t stream) {
    const int*   adj_rows = (const int*)  d_in[0];
    const int*   adj_cols = (const int*)  d_in[1];
    const float* adj_vals = (const float*)d_in[2];
    const float* x        = (const float*)d_in[3];
    const float* W        = (const float*)d_in[4];
    const float* b        = (const float*)d_in[5];
    float* out = (float*)d_out;

    char* ws = (char*)d_ws;
    __bf16*   Wt         = (__bf16*)  (ws + WT_OFF);
    unsigned* sup32      = (unsigned*)(ws + SUP_OFF);
    int2*     binbuf     = (int2*)    (ws + BIN_OFF);
    int*      bin_cursor = (int*)     (ws + CUR_OFF);

    k_prep<<<128, 256, 0, stream>>>(W, Wt, bin_cursor);
    k_gemm<<<782, 256, 0, stream>>>(x, Wt, sup32);
    k_bin <<<(N_EDGES + EDGES_PER_BLK - 1) / EDGES_PER_BLK, 256, 0, stream>>>
                (adj_rows, adj_cols, adj_vals, bin_cursor, binbuf);
    k_acc <<<NBINS, 1024, 0, stream>>>(bin_cursor, binbuf, sup32, b, out);
}

// Round 6
// 202.399 us; speedup vs baseline: 3.4370x; 3.4370x over previous
//
#include <hip/hip_runtime.h>
#include <hip/hip_bf16.h>

#define N_NODES 50000
#define N_EDGES 800000
#define IN_DIM  256
#define OUT_DIM 128

#define NBINS        256      // bins of 196 rows: 256*196 = 50176 >= 50000
#define ROWS_PER_BIN 196
#define BIN_CAP      3600     // mean 3125 + 8.5 sigma (sigma ~ 55.9)
#define EDGES_PER_BLK 4096    // k_bin tile

typedef __bf16 bf16x8 __attribute__((ext_vector_type(8)));
typedef float  f32x4  __attribute__((ext_vector_type(4)));

// bin = floor(row/196) via magic: (r*85599)>>24, exact for r < 50176 (verified R5)
__device__ __forceinline__ unsigned bin_of(unsigned r) { return (r * 85599u) >> 24; }

__device__ __forceinline__ float blo(unsigned u) { return __uint_as_float(u << 16); }
__device__ __forceinline__ float bhi(unsigned u) { return __uint_as_float(u & 0xffff0000u); }

// ---------------------------------------------------------------------------
// ws layout (bytes)
// ---------------------------------------------------------------------------
#define WT_OFF   0                      // 64 KB    : Wt bf16 [128][256]
#define SUP_OFF  65536                  // 12.8 MB  : support u32 [50000][64] planar-pair
#define BIN_OFF  12865536               // 7.37 MB  : binbuf int2[256*3600]
#define CUR_OFF  20238336               // 1 KB     : bin_cursor int[256]
#define RSD_OFF  20239360               // 401 KB   : rs_deg int2[50176]

// ---------------------------------------------------------------------------
// prep: Wt transpose+bf16; bin_cursor[b] = b*BIN_CAP
// ---------------------------------------------------------------------------
__global__ void k_prep(const float* __restrict__ W, __bf16* __restrict__ Wt,
                       int* __restrict__ bin_cursor) {
    int t = blockIdx.x * 256 + threadIdx.x;
    if (t < 32768) { int n = t >> 8, k = t & 255; Wt[t] = (__bf16)W[k * OUT_DIM + n]; }
    if (t < NBINS) bin_cursor[t] = t * BIN_CAP;
}

// ---------------------------------------------------------------------------
// support = x @ W  (bf16 MFMA, fp32 accum), planar-pair epilogue:
// word j of row = bf16(ch j) | bf16(ch j+64)<<16.   (verified R5)
// ---------------------------------------------------------------------------
__global__ __launch_bounds__(256) void k_gemm(const float* __restrict__ x,
                                              const __bf16* __restrict__ Wt,
                                              unsigned* __restrict__ sup32) {
    int wave = threadIdx.x >> 6;
    int lane = threadIdx.x & 63;
    int tile = blockIdx.x * 4 + wave;
    if (tile >= 3125) return;
    int r0   = tile * 16;
    int m    = lane & 15;
    int quad = lane >> 4;

    f32x4 acc[8];
#pragma unroll
    for (int i = 0; i < 8; ++i) acc[i] = (f32x4){0.f, 0.f, 0.f, 0.f};

    const float*  xp = x  + (long)(r0 + m) * IN_DIM + quad * 8;
    const __bf16* wp = Wt + m * IN_DIM + quad * 8;

#pragma unroll
    for (int ks = 0; ks < 8; ++ks) {
        float4 a0 = *(const float4*)(xp + ks * 32);
        float4 a1 = *(const float4*)(xp + ks * 32 + 4);
        bf16x8 a;
        a[0] = (__bf16)a0.x; a[1] = (__bf16)a0.y;
        a[2] = (__bf16)a0.z; a[3] = (__bf16)a0.w;
        a[4] = (__bf16)a1.x; a[5] = (__bf16)a1.y;
        a[6] = (__bf16)a1.z; a[7] = (__bf16)a1.w;
#pragma unroll
        for (int nt = 0; nt < 8; ++nt) {
            bf16x8 bfr = *(const bf16x8*)(wp + nt * 16 * IN_DIM + ks * 32);
            acc[nt] = __builtin_amdgcn_mfma_f32_16x16x32_bf16(a, bfr, acc[nt], 0, 0, 0);
        }
    }

    unsigned* op = sup32 + (long)r0 * 64;
#pragma unroll
    for (int nt = 0; nt < 4; ++nt) {
#pragma unroll
        for (int r = 0; r < 4; ++r) {
            __bf16 lo = (__bf16)acc[nt][r];
            __bf16 hi = (__bf16)acc[nt + 4][r];
            unsigned ul = *(unsigned short*)&lo;
            unsigned uh = *(unsigned short*)&hi;
            op[(quad * 4 + r) * 64 + nt * 16 + m] = ul | (uh << 16);
        }
    }
}

// ---------------------------------------------------------------------------
// k_bin: LDS-staged bin scatter (verified R5). count -> scan -> LDS scatter ->
// one global reservation atomic per bin -> coalesced copy-out.
// ---------------------------------------------------------------------------
__global__ __launch_bounds__(256) void k_bin(const int* __restrict__ rows,
                                             const int* __restrict__ cols,
                                             const float* __restrict__ vals,
                                             int* __restrict__ bin_cursor,
                                             int2* __restrict__ binbuf) {
    __shared__ int2 stage[EDGES_PER_BLK];          // 32 KB
    __shared__ int  cnt[NBINS], off[NBINS], base[NBINS], cur[NBINS], s[NBINS];
    int t = threadIdx.x;
    long e0 = (long)blockIdx.x * EDGES_PER_BLK;

    cnt[t] = 0;
    __syncthreads();

#pragma unroll
    for (int k = 0; k < 16; ++k) {
        long e = e0 + k * 256 + t;
        if (e < N_EDGES) atomicAdd(&cnt[bin_of((unsigned)rows[e])], 1);
    }
    __syncthreads();

    int v = cnt[t];
    s[t] = v; __syncthreads();
#pragma unroll
    for (int o = 1; o < 256; o <<= 1) {
        int xvl = (t >= o) ? s[t - o] : 0;
        __syncthreads();
        s[t] += xvl;
        __syncthreads();
    }
    off[t] = s[t] - v;
    cur[t] = s[t] - v;
    base[t] = atomicAdd(&bin_cursor[t], v);
    __syncthreads();

#pragma unroll
    for (int k = 0; k < 16; ++k) {
        long e = e0 + k * 256 + t;
        if (e < N_EDGES) {
            unsigned r = (unsigned)rows[e];
            unsigned c = (unsigned)cols[e];
            float    w = vals[e];
            int pos = atomicAdd(&cur[bin_of(r)], 1);
            stage[pos] = make_int2((int)((r << 16) | c), __float_as_int(w));
        }
    }
    __syncthreads();

    int nblk = (int)((N_EDGES - e0) < EDGES_PER_BLK ? (N_EDGES - e0) : EDGES_PER_BLK);
    for (int i = t; i < nblk; i += 256) {
        int2 rec = stage[i];
        unsigned bn = bin_of(((unsigned)rec.x) >> 16);
        int dst = base[bn] + (i - off[bn]);
        if (dst < (int)(bn + 1) * BIN_CAP)
            binbuf[dst] = rec;
    }
}

// ---------------------------------------------------------------------------
// k_bin2: per-bin LDS counting sort -> CSR order, sequential write-back.
// Only int LDS atomics (HW ds_add_u32). Writes rs_deg = {abs start, deg}.
// ---------------------------------------------------------------------------
__global__ __launch_bounds__(256) void k_bin2(const int* __restrict__ bin_cursor,
                                              int2* __restrict__ binbuf,
                                              int2* __restrict__ rs_deg) {
    __shared__ int2 stage[BIN_CAP];                // 28.8 KB
    __shared__ int2 sorted_[BIN_CAP];              // 28.8 KB
    __shared__ int  cnt[256], off[256], cur[256], s[256];
    int b = blockIdx.x, t = threadIdx.x;
    int row0 = b * ROWS_PER_BIN;

    int n = bin_cursor[b] - b * BIN_CAP;
    n = n < 0 ? 0 : (n > BIN_CAP ? BIN_CAP : n);
    int2* seg = binbuf + (long)b * BIN_CAP;

    cnt[t] = 0;
    __syncthreads();

    // load + histogram (rl in [0,196))
    for (int i = t; i < n; i += 256) {
        int2 rec = seg[i];
        stage[i] = rec;
        int rl = (int)(((unsigned)rec.x) >> 16) - row0;
        atomicAdd(&cnt[rl], 1);
    }
    __syncthreads();

    // exclusive scan of 256 counters
    int v = cnt[t];
    s[t] = v; __syncthreads();
#pragma unroll
    for (int o = 1; o < 256; o <<= 1) {
        int xvl = (t >= o) ? s[t - o] : 0;
        __syncthreads();
        s[t] += xvl;
        __syncthreads();
    }
    off[t] = s[t] - v;
    cur[t] = 0;
    __syncthreads();

    // scatter into sorted LDS stage
    for (int i = t; i < n; i += 256) {
        int2 rec = stage[i];
        int rl = (int)(((unsigned)rec.x) >> 16) - row0;
        int p = off[rl] + atomicAdd(&cur[rl], 1);
        sorted_[p] = rec;
    }
    __syncthreads();

    // sequential copy-back + rs_deg
    for (int i = t; i < n; i += 256)
        seg[i] = sorted_[i];
    if (t < ROWS_PER_BIN) {
        int row = row0 + t;
        if (row < N_NODES)
            rs_deg[row] = make_int2(b * BIN_CAP + off[t], cnt[t]);
    }
}

// ---------------------------------------------------------------------------
// Row-gather (R3-proven): 1 wave per row, planar-pair support word per lane,
// 4-deep MLP unroll, bias fused.
// ---------------------------------------------------------------------------
__global__ __launch_bounds__(256) void k_gather(const int2* __restrict__ rs_deg,
                                                const int2* __restrict__ edge_s,
                                                const unsigned* __restrict__ sup,
                                                const float* __restrict__ b,
                                                float* __restrict__ out) {
    int row = blockIdx.x * 4 + (threadIdx.x >> 6);
    if (row >= N_NODES) return;
    int lane = threadIdx.x & 63;
    int2 rd = rs_deg[row];
    int s = rd.x, n = rd.y;
    float a0 = 0.f, a1 = 0.f;

    int i = 0;
    for (; i + 4 <= n; i += 4) {
        int2 e0 = edge_s[s + i];
        int2 e1 = edge_s[s + i + 1];
        int2 e2 = edge_s[s + i + 2];
        int2 e3 = edge_s[s + i + 3];
        unsigned c0 = ((unsigned)e0.x) & 0xffffu;
        unsigned c1 = ((unsigned)e1.x) & 0xffffu;
        unsigned c2 = ((unsigned)e2.x) & 0xffffu;
        unsigned c3 = ((unsigned)e3.x) & 0xffffu;
        unsigned u0 = sup[(long)c0 * 64 + lane];
        unsigned u1 = sup[(long)c1 * 64 + lane];
        unsigned u2 = sup[(long)c2 * 64 + lane];
        unsigned u3 = sup[(long)c3 * 64 + lane];
        float v0 = __int_as_float(e0.y), v1 = __int_as_float(e1.y);
        float v2 = __int_as_float(e2.y), v3 = __int_as_float(e3.y);
        a0 += v0 * blo(u0); a1 += v0 * bhi(u0);
        a0 += v1 * blo(u1); a1 += v1 * bhi(u1);
        a0 += v2 * blo(u2); a1 += v2 * bhi(u2);
        a0 += v3 * blo(u3); a1 += v3 * bhi(u3);
    }
    for (; i < n; ++i) {
        int2 e0 = edge_s[s + i];
        unsigned c0 = ((unsigned)e0.x) & 0xffffu;
        unsigned u0 = sup[(long)c0 * 64 + lane];
        float v0 = __int_as_float(e0.y);
        a0 += v0 * blo(u0); a1 += v0 * bhi(u0);
    }
    // out channels: lane -> {lane, lane+64} (planar-pair); bias fused
    out[(long)row * 128 + lane]      = a0 + b[lane];
    out[(long)row * 128 + 64 + lane] = a1 + b[64 + lane];
}

// ---------------------------------------------------------------------------
extern "C" void kernel_launch(void* const* d_in, const int* in_sizes, int n_in,
                              void* d_out, int out_size, void* d_ws, size_t ws_size,
                              hipStream_t stream) {
    const int*   adj_rows = (const int*)  d_in[0];
    const int*   adj_cols = (const int*)  d_in[1];
    const float* adj_vals = (const float*)d_in[2];
    const float* x        = (const float*)d_in[3];
    const float* W        = (const float*)d_in[4];
    const float* b        = (const float*)d_in[5];
    float* out = (float*)d_out;

    char* ws = (char*)d_ws;
    __bf16*   Wt         = (__bf16*)  (ws + WT_OFF);
    unsigned* sup32      = (unsigned*)(ws + SUP_OFF);
    int2*     binbuf     = (int2*)    (ws + BIN_OFF);
    int*      bin_cursor = (int*)     (ws + CUR_OFF);
    int2*     rs_deg     = (int2*)    (ws + RSD_OFF);

    k_prep  <<<128, 256, 0, stream>>>(W, Wt, bin_cursor);
    k_gemm  <<<782, 256, 0, stream>>>(x, Wt, sup32);
    k_bin   <<<(N_EDGES + EDGES_PER_BLK - 1) / EDGES_PER_BLK, 256, 0, stream>>>
                 (adj_rows, adj_cols, adj_vals, bin_cursor, binbuf);
    k_bin2  <<<NBINS, 256, 0, stream>>>(bin_cursor, binbuf, rs_deg);
    k_gather<<<12500, 256, 0, stream>>>(rs_deg, binbuf, sup32, b, out);
}

// Round 7
// 181.648 us; speedup vs baseline: 3.8296x; 1.1142x over previous
//
#include <hip/hip_runtime.h>
#include <hip/hip_bf16.h>

#define N_NODES 50000
#define N_EDGES 800000
#define IN_DIM  256
#define OUT_DIM 128

#define NBINS        256      // bins of 196 rows: 256*196 = 50176 >= 50000
#define ROWS_PER_BIN 196
#define BIN_CAP      3600     // mean 3125 + 8.5 sigma
#define EPB          2048     // edges per bin-block (21.5 KB LDS)
#define NB_BIN       391      // ceil(800000/2048)
#define NB_GEMM      1563     // ceil(6250 wave-jobs / 4)

typedef __bf16 bf16x8 __attribute__((ext_vector_type(8)));
typedef float  f32x4  __attribute__((ext_vector_type(4)));

// bin = floor(row/196) via magic: (r*85599)>>24, exact for r < 50176 (verified R5/R6)
__device__ __forceinline__ unsigned bin_of(unsigned r) { return (r * 85599u) >> 24; }
__device__ __forceinline__ float blo(unsigned u) { return __uint_as_float(u << 16); }
__device__ __forceinline__ float bhi(unsigned u) { return __uint_as_float(u & 0xffff0000u); }

// ---------------------------------------------------------------------------
// ws layout (bytes)
// ---------------------------------------------------------------------------
#define WT_OFF   0                      // 64 KB    : Wt bf16 [128][256]
#define SUP_OFF  65536                  // 12.8 MB  : support u32 [50000][64] planar-pair
#define BIN_OFF  12865536               // 7.37 MB  : binbuf int2[256*3600]
#define CUR_OFF  20238336               // 1 KB     : bin_cursor int[256]

// ---------------------------------------------------------------------------
// prep: Wt transpose+bf16; bin_cursor[b] = b*BIN_CAP
// ---------------------------------------------------------------------------
__global__ void k_prep(const float* __restrict__ W, __bf16* __restrict__ Wt,
                       int* __restrict__ bin_cursor) {
    int t = blockIdx.x * 256 + threadIdx.x;
    if (t < 32768) { int n = t >> 8, k = t & 255; Wt[t] = (__bf16)W[k * OUT_DIM + n]; }
    if (t < NBINS) bin_cursor[t] = t * BIN_CAP;
}

// ---------------------------------------------------------------------------
// Fused kernel: blocks [0, NB_BIN) do LDS-staged edge binning (R5/R6-verified
// structure, 2048-edge tiles); blocks [NB_BIN, NB_BIN+NB_GEMM) do the MFMA
// GEMM with N split in half per wave (6250 wave-jobs -> 2x TLP vs R6).
// Independent work; grid-fusion overlaps the latency-bound GEMM with bin.
// ---------------------------------------------------------------------------
__global__ __launch_bounds__(256) void k_fused(const float* __restrict__ x,
                                               const __bf16* __restrict__ Wt,
                                               unsigned* __restrict__ sup32,
                                               const int* __restrict__ rows,
                                               const int* __restrict__ cols,
                                               const float* __restrict__ vals,
                                               int* __restrict__ bin_cursor,
                                               int2* __restrict__ binbuf) {
    __shared__ int2 stage[EPB];                    // 16 KB
    __shared__ int  cnt[NBINS], off[NBINS], base[NBINS], cur[NBINS], s[NBINS]; // 5 KB
    int t = threadIdx.x;

    if (blockIdx.x < NB_BIN) {
        // ---------------- bin path ----------------
        long e0 = (long)blockIdx.x * EPB;
        cnt[t] = 0;
        __syncthreads();

#pragma unroll
        for (int k = 0; k < EPB / 256; ++k) {
            long e = e0 + k * 256 + t;
            if (e < N_EDGES) atomicAdd(&cnt[bin_of((unsigned)rows[e])], 1);
        }
        __syncthreads();

        int v = cnt[t];
        s[t] = v; __syncthreads();
#pragma unroll
        for (int o = 1; o < 256; o <<= 1) {
            int xv = (t >= o) ? s[t - o] : 0;
            __syncthreads();
            s[t] += xv;
            __syncthreads();
        }
        off[t] = s[t] - v;
        cur[t] = s[t] - v;
        base[t] = atomicAdd(&bin_cursor[t], v);    // one global atomic per bin
        __syncthreads();

#pragma unroll
        for (int k = 0; k < EPB / 256; ++k) {
            long e = e0 + k * 256 + t;
            if (e < N_EDGES) {
                unsigned r = (unsigned)rows[e];
                unsigned c = (unsigned)cols[e];
                float    w = vals[e];
                int pos = atomicAdd(&cur[bin_of(r)], 1);
                stage[pos] = make_int2((int)((r << 16) | c), __float_as_int(w));
            }
        }
        __syncthreads();

        long rem = N_EDGES - e0;
        int nblk = rem < EPB ? (int)rem : EPB;
        for (int i = t; i < nblk; i += 256) {
            int2 rec = stage[i];
            unsigned bn = bin_of(((unsigned)rec.x) >> 16);
            int dst = base[bn] + (i - off[bn]);
            if (dst < (int)(bn + 1) * BIN_CAP)     // statistical overflow guard
                binbuf[dst] = rec;
        }
    } else {
        // ---------------- gemm path (16 rows x 64 cols per wave) ----------------
        int wave = t >> 6;
        int lane = t & 63;
        int job  = (blockIdx.x - NB_BIN) * 4 + wave;
        if (job >= 6250) return;
        int tile = job >> 1;
        int h    = job & 1;
        int a    = h * 2;                          // nt set {a, a+1, a+4, a+5}
        int r0   = tile * 16;
        int m    = lane & 15;
        int quad = lane >> 4;

        f32x4 acc0 = (f32x4){0,0,0,0}, acc1 = (f32x4){0,0,0,0};
        f32x4 acc2 = (f32x4){0,0,0,0}, acc3 = (f32x4){0,0,0,0};

        const float*  xp = x  + (long)(r0 + m) * IN_DIM + quad * 8;
        const __bf16* wp = Wt + m * IN_DIM + quad * 8;
        const __bf16* wp0 = wp + (a)     * 16 * IN_DIM;
        const __bf16* wp1 = wp + (a + 1) * 16 * IN_DIM;
        const __bf16* wp2 = wp + (a + 4) * 16 * IN_DIM;
        const __bf16* wp3 = wp + (a + 5) * 16 * IN_DIM;

#pragma unroll
        for (int ks = 0; ks < 8; ++ks) {
            float4 a0 = *(const float4*)(xp + ks * 32);
            float4 a1 = *(const float4*)(xp + ks * 32 + 4);
            bf16x8 af;
            af[0] = (__bf16)a0.x; af[1] = (__bf16)a0.y;
            af[2] = (__bf16)a0.z; af[3] = (__bf16)a0.w;
            af[4] = (__bf16)a1.x; af[5] = (__bf16)a1.y;
            af[6] = (__bf16)a1.z; af[7] = (__bf16)a1.w;
            bf16x8 b0 = *(const bf16x8*)(wp0 + ks * 32);
            bf16x8 b1 = *(const bf16x8*)(wp1 + ks * 32);
            bf16x8 b2 = *(const bf16x8*)(wp2 + ks * 32);
            bf16x8 b3 = *(const bf16x8*)(wp3 + ks * 32);
            acc0 = __builtin_amdgcn_mfma_f32_16x16x32_bf16(af, b0, acc0, 0, 0, 0);
            acc1 = __builtin_amdgcn_mfma_f32_16x16x32_bf16(af, b1, acc1, 0, 0, 0);
            acc2 = __builtin_amdgcn_mfma_f32_16x16x32_bf16(af, b2, acc2, 0, 0, 0);
            acc3 = __builtin_amdgcn_mfma_f32_16x16x32_bf16(af, b3, acc3, 0, 0, 0);
        }

        // planar-pair epilogue: word j=(a+i)*16+m packs ch j (lo) and j+64 (hi)
        unsigned* op = sup32 + (long)r0 * 64;
#pragma unroll
        for (int r = 0; r < 4; ++r) {
            __bf16 l0 = (__bf16)acc0[r], h0 = (__bf16)acc2[r];
            __bf16 l1 = (__bf16)acc1[r], h1 = (__bf16)acc3[r];
            unsigned w0 = (unsigned)*(unsigned short*)&l0 |
                          ((unsigned)*(unsigned short*)&h0 << 16);
            unsigned w1 = (unsigned)*(unsigned short*)&l1 |
                          ((unsigned)*(unsigned short*)&h1 << 16);
            op[(quad * 4 + r) * 64 + (a)     * 16 + m] = w0;
            op[(quad * 4 + r) * 64 + (a + 1) * 16 + m] = w1;
        }
    }
}

// ---------------------------------------------------------------------------
// k_sg: fused per-bin counting sort + gather. One 1024-thread block per bin.
// Sort the bin's segment into LDS (int LDS atomics only), then 16 waves
// gather rows directly from the LDS-sorted stage (no copy-back, no rs_deg).
// 8-deep MLP unroll on the random support gathers.
// ---------------------------------------------------------------------------
__global__ __launch_bounds__(1024) void k_sg(const int* __restrict__ bin_cursor,
                                             const int2* __restrict__ binbuf,
                                             const unsigned* __restrict__ sup,
                                             const float* __restrict__ bias,
                                             float* __restrict__ out) {
    __shared__ int2 stage[BIN_CAP];                // 28.8 KB
    __shared__ int2 sorted_[BIN_CAP];              // 28.8 KB
    __shared__ int  cnt[256], off[256], cur[256], s[256];
    int b = blockIdx.x, t = threadIdx.x;
    int row0 = b * ROWS_PER_BIN;

    int n = bin_cursor[b] - b * BIN_CAP;
    n = n < 0 ? 0 : (n > BIN_CAP ? BIN_CAP : n);
    const int2* seg = binbuf + (long)b * BIN_CAP;

    if (t < 256) cnt[t] = 0;
    __syncthreads();

    // load + per-row histogram
    for (int i = t; i < n; i += 1024) {
        int2 rec = seg[i];
        stage[i] = rec;
        atomicAdd(&cnt[(int)(((unsigned)rec.x) >> 16) - row0], 1);
    }
    __syncthreads();

    // exclusive scan over 256 counters (first 256 threads; uniform barriers)
    int v = 0;
    if (t < 256) { v = cnt[t]; s[t] = v; }
    __syncthreads();
#pragma unroll
    for (int o = 1; o < 256; o <<= 1) {
        int xv = 0;
        if (t < 256 && t >= o) xv = s[t - o];
        __syncthreads();
        if (t < 256) s[t] += xv;
        __syncthreads();
    }
    if (t < 256) { off[t] = s[t] - v; cur[t] = 0; }
    __syncthreads();

    // scatter into sorted LDS stage
    for (int i = t; i < n; i += 1024) {
        int2 rec = stage[i];
        int rl = (int)(((unsigned)rec.x) >> 16) - row0;
        sorted_[off[rl] + atomicAdd(&cur[rl], 1)] = rec;
    }
    __syncthreads();

    // gather: wave w handles rows rl = w, w+16, ...
    int wave = t >> 6, lane = t & 63;
    float bb0 = bias[lane], bb1 = bias[64 + lane];

    for (int rl = wave; rl < ROWS_PER_BIN; rl += 16) {
        int row = row0 + rl;
        if (row >= N_NODES) continue;
        int st = off[rl], nd = cnt[rl];
        float a0 = 0.f, a1 = 0.f;
        int i = 0;
        for (; i + 8 <= nd; i += 8) {
            int2 e[8]; unsigned u[8];
#pragma unroll
            for (int j = 0; j < 8; ++j) e[j] = sorted_[st + i + j];
#pragma unroll
            for (int j = 0; j < 8; ++j)
                u[j] = sup[(long)(((unsigned)e[j].x) & 0xffffu) * 64 + lane];
#pragma unroll
            for (int j = 0; j < 8; ++j) {
                float vv = __int_as_float(e[j].y);
                a0 += vv * blo(u[j]); a1 += vv * bhi(u[j]);
            }
        }
        for (; i < nd; ++i) {
            int2 ev = sorted_[st + i];
            unsigned uu = sup[(long)(((unsigned)ev.x) & 0xffffu) * 64 + lane];
            float vv = __int_as_float(ev.y);
            a0 += vv * blo(uu); a1 += vv * bhi(uu);
        }
        out[(long)row * 128 + lane]      = a0 + bb0;
        out[(long)row * 128 + 64 + lane] = a1 + bb1;
    }
}

// ---------------------------------------------------------------------------
extern "C" void kernel_launch(void* const* d_in, const int* in_sizes, int n_in,
                              void* d_out, int out_size, void* d_ws, size_t ws_size,
                              hipStream_t stream) {
    const int*   adj_rows = (const int*)  d_in[0];
    const int*   adj_cols = (const int*)  d_in[1];
    const float* adj_vals = (const float*)d_in[2];
    const float* x        = (const float*)d_in[3];
    const float* W        = (const float*)d_in[4];
    const float* b        = (const float*)d_in[5];
    float* out = (float*)d_out;

    char* ws = (char*)d_ws;
    __bf16*   Wt         = (__bf16*)  (ws + WT_OFF);
    unsigned* sup32      = (unsigned*)(ws + SUP_OFF);
    int2*     binbuf     = (int2*)    (ws + BIN_OFF);
    int*      bin_cursor = (int*)     (ws + CUR_OFF);

    k_prep <<<128, 256, 0, stream>>>(W, Wt, bin_cursor);
    k_fused<<<NB_BIN + NB_GEMM, 256, 0, stream>>>(x, Wt, sup32,
                                                  adj_rows, adj_cols, adj_vals,
                                                  bin_cursor, binbuf);
    k_sg   <<<NBINS, 1024, 0, stream>>>(bin_cursor, binbuf, sup32, b, out);
}

// Round 9
// 171.863 us; speedup vs baseline: 4.0476x; 1.0569x over previous
//
#include <hip/hip_runtime.h>
#include <hip/hip_bf16.h>

#define N_NODES 50000
#define N_EDGES 800000
#define IN_DIM  256
#define OUT_DIM 128

#define NBINS        256      // bins of 196 rows: 256*196 = 50176 >= 50000
#define ROWS_PER_BIN 196
#define BIN_CAP      3600     // mean 3125 + 8.5 sigma
#define EPB          2048     // edges per bin-block
#define NB_BIN       391      // ceil(800000/2048)
#define NB_GEMM      1563     // ceil(3125 row-tiles / 2 per block)
#define APITCH       264      // LDS A-tile pitch in bf16 (528 B, 16B-aligned)

typedef __bf16 bf16x8 __attribute__((ext_vector_type(8)));
typedef float  f32x4  __attribute__((ext_vector_type(4)));

// bin = floor(row/196) via magic: (r*85599)>>24, exact for r < 50176 (verified R5-R7)
__device__ __forceinline__ unsigned bin_of(unsigned r) { return (r * 85599u) >> 24; }
__device__ __forceinline__ float blo(unsigned u) { return __uint_as_float(u << 16); }
__device__ __forceinline__ float bhi(unsigned u) { return __uint_as_float(u & 0xffff0000u); }

// ---------------------------------------------------------------------------
// ws layout (bytes)
// ---------------------------------------------------------------------------
#define WT_OFF   0                      // 64 KB    : Wt bf16 [128][256]
#define SUP_OFF  65536                  // 12.8 MB  : support u32 [50000][64] planar-pair
#define BIN_OFF  12865536               // 7.37 MB  : binbuf int2[256*3600]
#define CUR_OFF  20238336               // 1 KB     : bin_cursor int[256]

// ---------------------------------------------------------------------------
// prep: Wt transpose+bf16; bin_cursor[b] = b*BIN_CAP
// ---------------------------------------------------------------------------
__global__ void k_prep(const float* __restrict__ W, __bf16* __restrict__ Wt,
                       int* __restrict__ bin_cursor) {
    int t = blockIdx.x * 256 + threadIdx.x;
    if (t < 32768) { int n = t >> 8, k = t & 255; Wt[t] = (__bf16)W[k * OUT_DIM + n]; }
    if (t < NBINS) bin_cursor[t] = t * BIN_CAP;
}

// ---------------------------------------------------------------------------
// Fused kernel.
//  blocks [0, NB_BIN): LDS-staged edge binning (verified R5-R7).
//  blocks [NB_BIN, ..): GEMM with block-cooperative A-staging:
//    stage 32 contiguous x-rows (32 KB, coalesced float4 stream) -> bf16 LDS,
//    then 4 waves (2 per row-tile, 64 cols each) run ds_read_b128 A-frags +
//    L2-resident Wt B-frags + MFMA.
//  R8 bug fixed here: a row is 64 float4s (IN_DIM=256), so row = idx>>6 and
//  in-row bf16 offset = (idx&63)*4.  (R8 had idx>>4 -> LDS overflow + NaN.)
// ---------------------------------------------------------------------------
__global__ __launch_bounds__(256) void k_fused(const float* __restrict__ x,
                                               const __bf16* __restrict__ Wt,
                                               unsigned* __restrict__ sup32,
                                               const int* __restrict__ rows,
                                               const int* __restrict__ cols,
                                               const float* __restrict__ vals,
                                               int* __restrict__ bin_cursor,
                                               int2* __restrict__ binbuf) {
    __shared__ union {
        struct {
            int2 stage[EPB];                               // 16 KB
            int  cnt[NBINS], off[NBINS], base[NBINS], cur[NBINS], s[NBINS]; // 5 KB
        } bin;
        __bf16 a[32 * APITCH];                             // 16.9 KB
    } sh;
    int t = threadIdx.x;

    if (blockIdx.x < NB_BIN) {
        // ---------------- bin path (unchanged) ----------------
        long e0 = (long)blockIdx.x * EPB;
        sh.bin.cnt[t] = 0;
        __syncthreads();

#pragma unroll
        for (int k = 0; k < EPB / 256; ++k) {
            long e = e0 + k * 256 + t;
            if (e < N_EDGES) atomicAdd(&sh.bin.cnt[bin_of((unsigned)rows[e])], 1);
        }
        __syncthreads();

        int v = sh.bin.cnt[t];
        sh.bin.s[t] = v; __syncthreads();
#pragma unroll
        for (int o = 1; o < 256; o <<= 1) {
            int xv = (t >= o) ? sh.bin.s[t - o] : 0;
            __syncthreads();
            sh.bin.s[t] += xv;
            __syncthreads();
        }
        sh.bin.off[t] = sh.bin.s[t] - v;
        sh.bin.cur[t] = sh.bin.s[t] - v;
        sh.bin.base[t] = atomicAdd(&bin_cursor[t], v);
        __syncthreads();

#pragma unroll
        for (int k = 0; k < EPB / 256; ++k) {
            long e = e0 + k * 256 + t;
            if (e < N_EDGES) {
                unsigned r = (unsigned)rows[e];
                unsigned c = (unsigned)cols[e];
                float    w = vals[e];
                int pos = atomicAdd(&sh.bin.cur[bin_of(r)], 1);
                sh.bin.stage[pos] = make_int2((int)((r << 16) | c), __float_as_int(w));
            }
        }
        __syncthreads();

        long rem = N_EDGES - e0;
        int nblk = rem < EPB ? (int)rem : EPB;
        for (int i = t; i < nblk; i += 256) {
            int2 rec = sh.bin.stage[i];
            unsigned bn = bin_of(((unsigned)rec.x) >> 16);
            int dst = sh.bin.base[bn] + (i - sh.bin.off[bn]);
            if (dst < (int)(bn + 1) * BIN_CAP)
                binbuf[dst] = rec;
        }
    } else {
        // ---------------- gemm path ----------------
        int  gb = blockIdx.x - NB_BIN;                 // 0..1562
        int  tp = gb * 2;                              // first tile of the pair
        long r0 = (long)tp * 16;                       // first row staged

        // stage 32 rows of x (contiguous 32 KB) -> bf16 LDS tile.
        // 64 float4 per row; idx in [0,2048) covers 32 rows.
        const float4* xv = (const float4*)(x + r0 * IN_DIM);
#pragma unroll
        for (int it = 0; it < 8; ++it) {
            int idx = it * 256 + t;                    // float4 index, [0,2048)
            int row = idx >> 6;                        // 64 float4 per row (FIXED)
            int col = idx & 63;                        // float4 within row
            if (r0 + row < N_NODES) {
                float4 f = xv[idx];
                __bf16 c0 = (__bf16)f.x, c1 = (__bf16)f.y;
                __bf16 c2 = (__bf16)f.z, c3 = (__bf16)f.w;
                unsigned lo = (unsigned)*(unsigned short*)&c0 |
                              ((unsigned)*(unsigned short*)&c1 << 16);
                unsigned hi = (unsigned)*(unsigned short*)&c2 |
                              ((unsigned)*(unsigned short*)&c3 << 16);
                *(uint2*)(&sh.a[row * APITCH + col * 4]) = make_uint2(lo, hi);
            }
        }
        __syncthreads();

        int wave = t >> 6;
        int lane = t & 63;
        int tile = tp + (wave >> 1);
        if (tile >= 3125) return;                      // after the barrier: safe
        int h    = wave & 1;
        int a    = h * 2;                              // nt set {a, a+1, a+4, a+5}
        int m    = lane & 15;
        int quad = lane >> 4;

        f32x4 acc0 = (f32x4){0,0,0,0}, acc1 = (f32x4){0,0,0,0};
        f32x4 acc2 = (f32x4){0,0,0,0}, acc3 = (f32x4){0,0,0,0};

        const __bf16* ap  = sh.a + ((wave >> 1) * 16 + m) * APITCH + quad * 8;
        const __bf16* wp  = Wt + m * IN_DIM + quad * 8;
        const __bf16* wp0 = wp + (a)     * 16 * IN_DIM;
        const __bf16* wp1 = wp + (a + 1) * 16 * IN_DIM;
        const __bf16* wp2 = wp + (a + 4) * 16 * IN_DIM;
        const __bf16* wp3 = wp + (a + 5) * 16 * IN_DIM;

#pragma unroll
        for (int ks = 0; ks < 8; ++ks) {
            bf16x8 af = *(const bf16x8*)(ap + ks * 32);        // ds_read_b128
            bf16x8 b0 = *(const bf16x8*)(wp0 + ks * 32);
            bf16x8 b1 = *(const bf16x8*)(wp1 + ks * 32);
            bf16x8 b2 = *(const bf16x8*)(wp2 + ks * 32);
            bf16x8 b3 = *(const bf16x8*)(wp3 + ks * 32);
            acc0 = __builtin_amdgcn_mfma_f32_16x16x32_bf16(af, b0, acc0, 0, 0, 0);
            acc1 = __builtin_amdgcn_mfma_f32_16x16x32_bf16(af, b1, acc1, 0, 0, 0);
            acc2 = __builtin_amdgcn_mfma_f32_16x16x32_bf16(af, b2, acc2, 0, 0, 0);
            acc3 = __builtin_amdgcn_mfma_f32_16x16x32_bf16(af, b3, acc3, 0, 0, 0);
        }

        // planar-pair epilogue (verified R7): word j=(a+i)*16+m = ch j | ch j+64
        unsigned* op = sup32 + (long)tile * 16 * 64;
#pragma unroll
        for (int r = 0; r < 4; ++r) {
            __bf16 l0 = (__bf16)acc0[r], h0 = (__bf16)acc2[r];
            __bf16 l1 = (__bf16)acc1[r], h1 = (__bf16)acc3[r];
            unsigned w0 = (unsigned)*(unsigned short*)&l0 |
                          ((unsigned)*(unsigned short*)&h0 << 16);
            unsigned w1 = (unsigned)*(unsigned short*)&l1 |
                          ((unsigned)*(unsigned short*)&h1 << 16);
            op[(quad * 4 + r) * 64 + (a)     * 16 + m] = w0;
            op[(quad * 4 + r) * 64 + (a + 1) * 16 + m] = w1;
        }
    }
}

// ---------------------------------------------------------------------------
// k_sg: fused per-bin counting sort + gather (unchanged from R7, verified).
// ---------------------------------------------------------------------------
__global__ __launch_bounds__(1024) void k_sg(const int* __restrict__ bin_cursor,
                                             const int2* __restrict__ binbuf,
                                             const unsigned* __restrict__ sup,
                                             const float* __restrict__ bias,
                                             float* __restrict__ out) {
    __shared__ int2 stage[BIN_CAP];                // 28.8 KB
    __shared__ int2 sorted_[BIN_CAP];              // 28.8 KB
    __shared__ int  cnt[256], off[256], cur[256], s[256];
    int b = blockIdx.x, t = threadIdx.x;
    int row0 = b * ROWS_PER_BIN;

    int n = bin_cursor[b] - b * BIN_CAP;
    n = n < 0 ? 0 : (n > BIN_CAP ? BIN_CAP : n);
    const int2* seg = binbuf + (long)b * BIN_CAP;

    if (t < 256) cnt[t] = 0;
    __syncthreads();

    for (int i = t; i < n; i += 1024) {
        int2 rec = seg[i];
        stage[i] = rec;
        atomicAdd(&cnt[(int)(((unsigned)rec.x) >> 16) - row0], 1);
    }
    __syncthreads();

    int v = 0;
    if (t < 256) { v = cnt[t]; s[t] = v; }
    __syncthreads();
#pragma unroll
    for (int o = 1; o < 256; o <<= 1) {
        int xv = 0;
        if (t < 256 && t >= o) xv = s[t - o];
        __syncthreads();
        if (t < 256) s[t] += xv;
        __syncthreads();
    }
    if (t < 256) { off[t] = s[t] - v; cur[t] = 0; }
    __syncthreads();

    for (int i = t; i < n; i += 1024) {
        int2 rec = stage[i];
        int rl = (int)(((unsigned)rec.x) >> 16) - row0;
        sorted_[off[rl] + atomicAdd(&cur[rl], 1)] = rec;
    }
    __syncthreads();

    int wave = t >> 6, lane = t & 63;
    float bb0 = bias[lane], bb1 = bias[64 + lane];

    for (int rl = wave; rl < ROWS_PER_BIN; rl += 16) {
        int row = row0 + rl;
        if (row >= N_NODES) continue;
        int st = off[rl], nd = cnt[rl];
        float a0 = 0.f, a1 = 0.f;
        int i = 0;
        for (; i + 8 <= nd; i += 8) {
            int2 e[8]; unsigned u[8];
#pragma unroll
            for (int j = 0; j < 8; ++j) e[j] = sorted_[st + i + j];
#pragma unroll
            for (int j = 0; j < 8; ++j)
                u[j] = sup[(long)(((unsigned)e[j].x) & 0xffffu) * 64 + lane];
#pragma unroll
            for (int j = 0; j < 8; ++j) {
                float vv = __int_as_float(e[j].y);
                a0 += vv * blo(u[j]); a1 += vv * bhi(u[j]);
            }
        }
        for (; i < nd; ++i) {
            int2 ev = sorted_[st + i];
            unsigned uu = sup[(long)(((unsigned)ev.x) & 0xffffu) * 64 + lane];
            float vv = __int_as_float(ev.y);
            a0 += vv * blo(uu); a1 += vv * bhi(uu);
        }
        out[(long)row * 128 + lane]      = a0 + bb0;
        out[(long)row * 128 + 64 + lane] = a1 + bb1;
    }
}

// ---------------------------------------------------------------------------
extern "C" void kernel_launch(void* const* d_in, const int* in_sizes, int n_in,
                              void* d_out, int out_size, void* d_ws, size_t ws_size,
                              hipStream_t stream) {
    const int*   adj_rows = (const int*)  d_in[0];
    const int*   adj_cols = (const int*)  d_in[1];
    const float* adj_vals = (const float*)d_in[2];
    const float* x        = (const float*)d_in[3];
    const float* W        = (const float*)d_in[4];
    const float* b        = (const float*)d_in[5];
    float* out = (float*)d_out;

    char* ws = (char*)d_ws;
    __bf16*   Wt         = (__bf16*)  (ws + WT_OFF);
    unsigned* sup32      = (unsigned*)(ws + SUP_OFF);
    int2*     binbuf     = (int2*)    (ws + BIN_OFF);
    int*      bin_cursor = (int*)     (ws + CUR_OFF);

    k_prep <<<128, 256, 0, stream>>>(W, Wt, bin_cursor);
    k_fused<<<NB_BIN + NB_GEMM, 256, 0, stream>>>(x, Wt, sup32,
                                                  adj_rows, adj_cols, adj_vals,
                                                  bin_cursor, binbuf);
    k_sg   <<<NBINS, 1024, 0, stream>>>(bin_cursor, binbuf, sup32, b, out);
}